// Round 1
// baseline (41.474 us; speedup 1.0000x reference)
//
#include <hip/hip_runtime.h>
#include <hip/hip_bf16.h>

#define D 128
#define Nn 512
#define Bb 2

typedef __bf16 bf16x8_t __attribute__((ext_vector_type(8)));
typedef float f32x4_t __attribute__((ext_vector_type(4)));

// ---------------------------------------------------------------------------
// Kernel 1: A[b,i,e] = sum_d g[d]*W1[d][e] + b1[e];  C[b,i,e] = sum_d g[d]*W1[D+d][e]
// where g = dom*evo.  One block per (b,i), 256 threads (128 for A-half, 128 for C-half).
// ---------------------------------------------------------------------------
__global__ void precompute_ac(const float* __restrict__ dom,
                              const float* __restrict__ evo,
                              const float* __restrict__ W1,
                              const float* __restrict__ b1,
                              float* __restrict__ A,
                              float* __restrict__ C) {
    const int flat = blockIdx.x;            // b*Nn + i
    const int t = threadIdx.x;              // 0..255
    __shared__ float g[D];
    if (t < D) g[t] = dom[flat * D + t] * evo[flat * D + t];
    __syncthreads();
    const int half = t >> 7;                // 0 -> A, 1 -> C
    const int e = t & 127;
    const float* Wp = W1 + half * D * D;    // rows d' = half*D .. half*D+127
    float acc = 0.f;
#pragma unroll 8
    for (int dp = 0; dp < D; ++dp) acc = fmaf(g[dp], Wp[dp * D + e], acc);
    if (half == 0) A[flat * D + e] = acc + b1[e];
    else           C[flat * D + e] = acc;
}

// ---------------------------------------------------------------------------
// Kernel 2: per block: batch b, 4 consecutive i.  8 waves: wave>>1 picks i,
// wave&1 picks which 2 j-tiles of each 64-j chunk.  MFMA 16x16x32 bf16:
//   A-frag (M=j rows): lane holds H[j = lane&15][k = kk*32 + (lane>>4)*8 + e]
//   B-frag (N=e cols): lane holds W2[k][e = et*16 + (lane&15)]
//   C/D:               lane holds D[row = (lane>>4)*4 + r][col = lane&15]
// ---------------------------------------------------------------------------
__global__ __launch_bounds__(512, 2)
void coevo_main(const float* __restrict__ A,
                const float* __restrict__ C,
                const float* __restrict__ W2,
                const float* __restrict__ b2,
                const float* __restrict__ W3,
                const float* __restrict__ b3,
                float* __restrict__ out) {
    const int tid  = threadIdx.x;
    const int wave = tid >> 6;
    const int lane = tid & 63;
    const int m = lane & 15;                // fragment row/col index
    const int q = lane >> 4;                // k-group

    const int blk    = blockIdx.x;
    const int b      = blk >> 7;            // 128 blocks per batch
    const int i_base = (blk & 127) << 2;
    const int i      = i_base + (wave >> 1);
    const int jsel   = wave & 1;

    __shared__ float cs[64 * 132];          // 64 j-rows x 128 d, padded +4 f32

    // ---- per-lane A row (b1 folded): ab[kk*8+e] = A[b,i, kk*32 + q*8 + e]
    float ab[32];
    {
        const float* Ap = A + ((size_t)(b * Nn + i)) * D + q * 8;
#pragma unroll
        for (int kk = 0; kk < 4; ++kk) {
            f32x4_t v0 = *(const f32x4_t*)(Ap + kk * 32);
            f32x4_t v1 = *(const f32x4_t*)(Ap + kk * 32 + 4);
            ab[kk * 8 + 0] = v0[0]; ab[kk * 8 + 1] = v0[1];
            ab[kk * 8 + 2] = v0[2]; ab[kk * 8 + 3] = v0[3];
            ab[kk * 8 + 4] = v1[0]; ab[kk * 8 + 5] = v1[1];
            ab[kk * 8 + 6] = v1[2]; ab[kk * 8 + 7] = v1[3];
        }
    }

    // ---- W2 B-fragments (one-time): w2f[et][kk][e] = W2[kk*32+q*8+e][et*16+m]
    bf16x8_t w2f[4][4];
#pragma unroll
    for (int et = 0; et < 4; ++et) {
#pragma unroll
        for (int kk = 0; kk < 4; ++kk) {
            bf16x8_t w;
#pragma unroll
            for (int e = 0; e < 8; ++e) {
                int k = kk * 32 + q * 8 + e;
                w[e] = (__bf16)W2[k * 64 + et * 16 + m];
            }
            w2f[et][kk] = w;
        }
    }

    // ---- epilogue constants for this lane's columns e = et*16 + m
    float b2v[4], w3v[4];
#pragma unroll
    for (int et = 0; et < 4; ++et) {
        b2v[et] = b2[et * 16 + m];
        w3v[et] = W3[et * 16 + m];
    }
    const float b3s = b3[0];

    const float* Cb = C + (size_t)b * Nn * D;

    for (int chunk = 0; chunk < 8; ++chunk) {
        __syncthreads();   // protect LDS from previous iteration's readers
        // ---- stage 64 j-rows of C into LDS (padded rows)
#pragma unroll
        for (int it = 0; it < 4; ++it) {
            int f  = it * 512 + tid;        // float4 index 0..2047
            int r  = f >> 5;                // j row within chunk
            int c4 = f & 31;                // float4 within row
            f32x4_t v = *(const f32x4_t*)(Cb + chunk * 64 * D + f * 4);
            *(f32x4_t*)(&cs[r * 132 + c4 * 4]) = v;
        }
        __syncthreads();

#pragma unroll
        for (int jt2 = 0; jt2 < 2; ++jt2) {
            const int jtile = jsel * 2 + jt2;
            const int jrow  = jtile * 16 + m;      // this lane's j row (A-frag)
            const float* cp = &cs[jrow * 132 + q * 8];

            // ---- build H fragments: h = relu(a + c) (b1 folded into a)
            bf16x8_t af[4];
#pragma unroll
            for (int kk = 0; kk < 4; ++kk) {
                f32x4_t c0 = *(const f32x4_t*)(cp + kk * 32);
                f32x4_t c1 = *(const f32x4_t*)(cp + kk * 32 + 4);
                bf16x8_t h;
                h[0] = (__bf16)fmaxf(ab[kk * 8 + 0] + c0[0], 0.f);
                h[1] = (__bf16)fmaxf(ab[kk * 8 + 1] + c0[1], 0.f);
                h[2] = (__bf16)fmaxf(ab[kk * 8 + 2] + c0[2], 0.f);
                h[3] = (__bf16)fmaxf(ab[kk * 8 + 3] + c0[3], 0.f);
                h[4] = (__bf16)fmaxf(ab[kk * 8 + 4] + c1[0], 0.f);
                h[5] = (__bf16)fmaxf(ab[kk * 8 + 5] + c1[1], 0.f);
                h[6] = (__bf16)fmaxf(ab[kk * 8 + 6] + c1[2], 0.f);
                h[7] = (__bf16)fmaxf(ab[kk * 8 + 7] + c1[3], 0.f);
                af[kk] = h;
            }

            // ---- GEMM: [16j x 128k] @ [128k x 64e]
            f32x4_t acc[4];
#pragma unroll
            for (int et = 0; et < 4; ++et) {
                f32x4_t a = {0.f, 0.f, 0.f, 0.f};
#pragma unroll
                for (int kk = 0; kk < 4; ++kk)
                    a = __builtin_amdgcn_mfma_f32_16x16x32_bf16(af[kk], w2f[et][kk], a, 0, 0, 0);
                acc[et] = a;
            }

            // ---- epilogue: relu(+b2), dot W3 over e (16 lanes x 4 tiles), sigmoid
            float part[4];
#pragma unroll
            for (int r = 0; r < 4; ++r) {
                float p = 0.f;
#pragma unroll
                for (int et = 0; et < 4; ++et) {
                    float h2 = fmaxf(acc[et][r] + b2v[et], 0.f);
                    p = fmaf(h2, w3v[et], p);
                }
                part[r] = p;
            }
#pragma unroll
            for (int off = 8; off >= 1; off >>= 1) {
#pragma unroll
                for (int r = 0; r < 4; ++r)
                    part[r] += __shfl_xor(part[r], off, 64);
            }

            if (m == 0) {
                const int j0 = chunk * 64 + jtile * 16 + q * 4;
#pragma unroll
                for (int r = 0; r < 4; ++r) {
                    const int j = j0 + r;
                    if (j > i) {
                        float sv = 1.f / (1.f + expf(-(part[r] + b3s)));
                        out[((size_t)b * Nn + i) * Nn + j] = sv;
                        out[((size_t)b * Nn + j) * Nn + i] = sv;
                    } else if (j == i) {
                        out[((size_t)b * Nn + i) * Nn + j] = 0.f;
                    }
                }
            }
        }
    }
}

extern "C" void kernel_launch(void* const* d_in, const int* in_sizes, int n_in,
                              void* d_out, int out_size, void* d_ws, size_t ws_size,
                              hipStream_t stream) {
    const float* dom = (const float*)d_in[0];
    const float* evo = (const float*)d_in[1];
    const float* W1  = (const float*)d_in[2];
    const float* b1  = (const float*)d_in[3];
    const float* W2  = (const float*)d_in[4];
    const float* b2  = (const float*)d_in[5];
    const float* W3  = (const float*)d_in[6];
    const float* b3  = (const float*)d_in[7];
    float* out = (float*)d_out;

    float* A = (float*)d_ws;                       // [B][N][D] f32
    float* C = A + (size_t)Bb * Nn * D;            // [B][N][D] f32

    precompute_ac<<<Bb * Nn, 256, 0, stream>>>(dom, evo, W1, b1, A, C);
    coevo_main<<<Bb * Nn / 4, 512, 0, stream>>>(A, C, W2, b2, W3, b3, out);
}